// Round 16
// baseline (451.275 us; speedup 1.0000x reference)
//
#include <hip/hip_runtime.h>

// Problem constants: B=4, T=2048, C=2048, H=16, D=128
#define T_SEQ 2048
#define DHEAD 128
#define NHEAD 16
#define CDIM  2048
#define BATCH 4

typedef __bf16 v8bf __attribute__((ext_vector_type(8)));
typedef __bf16 v4bf __attribute__((ext_vector_type(4)));
typedef __bf16 v2bf __attribute__((ext_vector_type(2)));
typedef float  v4f  __attribute__((ext_vector_type(4)));

#define MFMA16(a,b,c) __builtin_amdgcn_mfma_f32_16x16x32_bf16(a,b,c,0,0,0)
#define GLDS16(g,l) __builtin_amdgcn_global_load_lds( \
    (__attribute__((address_space(1))) void*)(g), \
    (__attribute__((address_space(3))) void*)(l), 16, 0, 0)

// ------- fused f32 -> bf16 convert (x, w_attn, w_proj) + RoPE table ---------
__global__ __launch_bounds__(256) void cvt_all(const float* __restrict__ x,
                                               const float* __restrict__ wa,
                                               const float* __restrict__ wp,
                                               __bf16* __restrict__ xo,
                                               __bf16* __restrict__ wao,
                                               __bf16* __restrict__ wpo,
                                               float2* __restrict__ rt) {
  int i = blockIdx.x * 256 + threadIdx.x;
  int stride = gridDim.x * 256;
  for (int j = i; j < 8519680; j += stride) {   // 8388608 float4s + 131072 tab
    if (j < 8388608) {
      const float* src; __bf16* dst; int off;
      if (j < 4194304)      { src = x;  dst = xo;  off = j; }
      else if (j < 7340032) { src = wa; dst = wao; off = j - 4194304; }
      else                  { src = wp; dst = wpo; off = j - 7340032; }
      float4 v = *(const float4*)(src + (size_t)off * 4);
      v4bf o = {(__bf16)v.x, (__bf16)v.y, (__bf16)v.z, (__bf16)v.w};
      *(v4bf*)(dst + (size_t)off * 4) = o;
    } else {
      int e = j - 8388608;                     // 0..131071
      int tt = e >> 6, jj = e & 63;
      float invf = exp2f((float)jj * (-13.287712379549449f / 64.f));
      float ang = (float)tt * invf;
      float c = cosf(ang), s = sinf(ang);
      rt[e] = make_float2(c + s, c - s);
    }
  }
}

// =============== shared GEMM pieces =========================================
#define LGKM0() { asm volatile("s_waitcnt lgkmcnt(0)" ::: "memory"); \
                  __builtin_amdgcn_sched_barrier(0); }
#define BARR()  { __builtin_amdgcn_s_barrier(); __builtin_amdgcn_sched_barrier(0); }

#define RDA(mm, kk) (*(const v8bf*)(bA + (wm16 + (mm)*32 + lr) * 128 + ((((kk)*64) + lgc) ^ swl)))
#define RDB(n, kk)  (*(const v8bf*)(bB + (wn64 + (n)*16 + lr) * 128 + ((((kk)*64) + lgc) ^ swl)))
#define MF(mm,n,kk) acc[mm][n] = MFMA16(af[(mm)&1][kk], bfr[n][kk], acc[mm][n]);

#define PH_MFMA(MM0, MM1) \
  BARR(); LGKM0(); \
  __builtin_amdgcn_s_setprio(1); \
  MF(MM0,0,0) MF(MM0,1,0) MF(MM0,2,0) MF(MM0,3,0) \
  MF(MM1,0,0) MF(MM1,1,0) MF(MM1,2,0) MF(MM1,3,0) \
  MF(MM0,0,1) MF(MM0,1,1) MF(MM0,2,1) MF(MM0,3,1) \
  MF(MM1,0,1) MF(MM1,1,1) MF(MM1,2,1) MF(MM1,3,1) \
  __builtin_amdgcn_s_setprio(0); \
  BARR();

// ---- core A (glds A+B, m201 schedule) — used by gemm_out8 ------------------
#define STAGE_H(SRC, ks, hh, LBASE) { \
  GLDS16((SRC) + (size_t)((hh)*128)      * 2048 + (size_t)(ks)*64, lds + (LBASE) + dst0); \
  GLDS16((SRC) + (size_t)((hh)*128 + 64) * 2048 + (size_t)(ks)*64, lds + (LBASE) + 4096 + dst0); }

#define TILE(CB, ks1, ks2) { \
  const char* bA = (const char*)(lds + (CB)*32768); \
  const char* bB = bA + 32768; \
  v8bf bfr[4][2], af[2][2]; \
  af[0][0]=RDA(0,0); af[0][1]=RDA(0,1); af[1][0]=RDA(1,0); af[1][1]=RDA(1,1); \
  bfr[0][0]=RDB(0,0); bfr[0][1]=RDB(0,1); bfr[1][0]=RDB(1,0); bfr[1][1]=RDB(1,1); \
  bfr[2][0]=RDB(2,0); bfr[2][1]=RDB(2,1); bfr[3][0]=RDB(3,0); bfr[3][1]=RDB(3,1); \
  STAGE_H(Asrc, ks1, 1, ((CB)^1)*32768 + 8192); \
  PH_MFMA(0, 1) \
  af[0][0]=RDA(2,0); af[0][1]=RDA(2,1); af[1][0]=RDA(3,0); af[1][1]=RDA(3,1); \
  STAGE_H(Bsrc, ks2, 0, (CB)*32768 + 16384); \
  PH_MFMA(2, 3) \
  af[0][0]=RDA(4,0); af[0][1]=RDA(4,1); af[1][0]=RDA(5,0); af[1][1]=RDA(5,1); \
  STAGE_H(Asrc, ks2, 0, (CB)*32768); \
  PH_MFMA(4, 5) \
  af[0][0]=RDA(6,0); af[0][1]=RDA(6,1); af[1][0]=RDA(7,0); af[1][1]=RDA(7,1); \
  STAGE_H(Bsrc, ks2, 1, (CB)*32768 + 24576); \
  asm volatile("s_waitcnt vmcnt(6)" ::: "memory"); \
  PH_MFMA(6, 7) \
}

__device__ __forceinline__ void gemm256_core(
    const __bf16* __restrict__ A, const __bf16* __restrict__ Bm,
    int row0, int col0, __bf16* lds, v4f (&acc)[8][4],
    int wm16, int wn64, int lr, int lg) {
  int t = threadIdx.x;
  int wid = t >> 6;
  int lgc = lg * 16;
  int swl = (lr & 7) << 4;
#pragma unroll
  for (int mm = 0; mm < 8; ++mm)
#pragma unroll
    for (int n = 0; n < 4; ++n) acc[mm][n] = (v4f){0.f, 0.f, 0.f, 0.f};

  int srow = t >> 3;
  int scol = (((t & 7) ^ ((t >> 3) & 7)) << 3);
  const __bf16* Asrc = A  + (size_t)(row0 + srow) * 2048 + scol;
  const __bf16* Bsrc = Bm + (size_t)(col0 + srow) * 2048 + scol;
  int dst0 = wid << 9;

  STAGE_H(Asrc, 0, 0, 0);
  STAGE_H(Asrc, 0, 1, 8192);
  STAGE_H(Bsrc, 0, 0, 16384);
  STAGE_H(Bsrc, 0, 1, 24576);
  STAGE_H(Bsrc, 1, 0, 32768 + 16384);
  STAGE_H(Asrc, 1, 0, 32768);
  STAGE_H(Bsrc, 1, 1, 32768 + 24576);
  asm volatile("s_waitcnt vmcnt(6)" ::: "memory");
  BARR();

  for (int m = 0; m < 32; m += 2) {
    TILE(0, m + 1, (m + 2) & 31)
    TILE(1, (m + 2) & 31, (m + 3) & 31)
  }
  asm volatile("s_waitcnt vmcnt(0)" ::: "memory");
}

// ---- core Q (r16): A via glds (L2-hot), B via 2-tile-lookahead REG staging -
// Per tile t: ph1 ds_write B(t+1) regs->bufB[CB^1] (layout identical to glds
// path), reads, glds A(t+1) h0/h1; ph2 glds A h2/h3; ph3 load B(t+2) j0/j1 to
// regs; ph4 load j2/j3 + vmcnt(4) (A done, B regs stay outstanding - compiler
// inserts its own counted wait before next tile's ds_write). FIFO order A
// before B within each tile makes vmcnt(4) skip exactly the B loads.
#define STAGE_A2(ks, CB, HH) { \
  GLDS16(Asrc + (size_t)((HH)*128)      * 2048 + (size_t)(ks)*64, lds + (CB)*32768 + (HH)*8192 + dst0); \
  GLDS16(Asrc + (size_t)((HH)*128 + 64) * 2048 + (size_t)(ks)*64, lds + (CB)*32768 + (HH)*8192 + 4096 + dst0); }

#define LOAD_B2A(R, ks) { \
  R##0 = *(const v8bf*)(Bsrc + (size_t)(ks)*64); \
  R##1 = *(const v8bf*)(Bsrc + (size_t)64*2048 + (size_t)(ks)*64); }
#define LOAD_B2B(R, ks) { \
  R##2 = *(const v8bf*)(Bsrc + (size_t)128*2048 + (size_t)(ks)*64); \
  R##3 = *(const v8bf*)(Bsrc + (size_t)192*2048 + (size_t)(ks)*64); }

#define WRITE_B2(R, CB) { \
  char* dWB = (char*)lds + (CB)*65536 + 32768 + tid16; \
  *(v8bf*)(dWB)         = R##0; \
  *(v8bf*)(dWB +  8192) = R##1; \
  *(v8bf*)(dWB + 16384) = R##2; \
  *(v8bf*)(dWB + 24576) = R##3; }

#define TILE_Q(CB, RW, RL, ksA, ksB) { \
  const char* bA = (const char*)lds + (CB)*65536; \
  const char* bB = bA + 32768; \
  WRITE_B2(RW, (CB)^1); \
  v8bf bfr[4][2], af[2][2]; \
  af[0][0]=RDA(0,0); af[0][1]=RDA(0,1); af[1][0]=RDA(1,0); af[1][1]=RDA(1,1); \
  bfr[0][0]=RDB(0,0); bfr[0][1]=RDB(0,1); bfr[1][0]=RDB(1,0); bfr[1][1]=RDB(1,1); \
  bfr[2][0]=RDB(2,0); bfr[2][1]=RDB(2,1); bfr[3][0]=RDB(3,0); bfr[3][1]=RDB(3,1); \
  STAGE_A2(ksA, (CB)^1, 0); \
  PH_MFMA(0, 1) \
  af[0][0]=RDA(2,0); af[0][1]=RDA(2,1); af[1][0]=RDA(3,0); af[1][1]=RDA(3,1); \
  STAGE_A2(ksA, (CB)^1, 1); \
  PH_MFMA(2, 3) \
  af[0][0]=RDA(4,0); af[0][1]=RDA(4,1); af[1][0]=RDA(5,0); af[1][1]=RDA(5,1); \
  __builtin_amdgcn_sched_barrier(0); \
  LOAD_B2A(RL, ksB); \
  PH_MFMA(4, 5) \
  af[0][0]=RDA(6,0); af[0][1]=RDA(6,1); af[1][0]=RDA(7,0); af[1][1]=RDA(7,1); \
  LOAD_B2B(RL, ksB); \
  asm volatile("s_waitcnt vmcnt(4)" ::: "memory"); \
  PH_MFMA(6, 7) \
}

__device__ __forceinline__ void gemm256q_core(
    const __bf16* __restrict__ A, const __bf16* __restrict__ Bm,
    int row0, int col0, __bf16* lds, v4f (&acc)[8][4],
    int wm16, int wn64, int lr, int lg) {
  int t = threadIdx.x;
  int wid = t >> 6;
  int lgc = lg * 16;
  int swl = (lr & 7) << 4;
  int tid16 = t * 16;
#pragma unroll
  for (int mm = 0; mm < 8; ++mm)
#pragma unroll
    for (int n = 0; n < 4; ++n) acc[mm][n] = (v4f){0.f, 0.f, 0.f, 0.f};

  int srow = t >> 3;
  int scol = (((t & 7) ^ ((t >> 3) & 7)) << 3);
  const __bf16* Asrc = A  + (size_t)(row0 + srow) * 2048 + scol;
  const __bf16* Bsrc = Bm + (size_t)(col0 + srow) * 2048 + scol;
  int dst0 = wid << 9;

  v8bf bx0, bx1, bx2, bx3, by0, by1, by2, by3;

  // prologue: B(0)->regs, A(0)->glds, write B0, B(1)->regs, wait A0, barrier
  LOAD_B2A(by, 0); LOAD_B2B(by, 0);              // B(0)
  __builtin_amdgcn_sched_barrier(0);
  STAGE_A2(0, 0, 0); STAGE_A2(0, 0, 1);          // A(0) -> bufA0
  __builtin_amdgcn_sched_barrier(0);
  WRITE_B2(by, 0);                               // compiler waits B(0) loads
  LOAD_B2A(by, 1); LOAD_B2B(by, 1);              // B(1) (order: A0 then B1)
  asm volatile("s_waitcnt vmcnt(4)" ::: "memory");   // A(0) landed
  asm volatile("s_waitcnt lgkmcnt(0)" ::: "memory"); // publish B0 writes
  BARR();

  // steady state: tile t computes buf t&1; by/bx alternate as B-reg carriers.
  for (int m = 0; m < 32; m += 2) {
    TILE_Q(0, by, bx, (m + 1) & 31, (m + 2) & 31)
    TILE_Q(1, bx, by, (m + 2) & 31, (m + 3) & 31)
  }
  asm volatile("s_waitcnt vmcnt(0)" ::: "memory");
}

// GEMM1: qkv = x * w_attn^T + b_attn.  (r16: core Q, launch_bounds (512,1) —
// LDS caps at 1 block/CU anyway; lifts VGPR cap for the B-reg carriers.)
// Q/K: fused bias+RoPE epilogue, lane = column-pair (r12).
// V: LDS-transposed coalesced store to Vt (BH,D,T).
__global__ __launch_bounds__(512, 1) void gemm_qkv8(
    const __bf16* __restrict__ A, const __bf16* __restrict__ Bm,
    const float* __restrict__ bias, const float2* __restrict__ rt,
    __bf16* __restrict__ Qb, __bf16* __restrict__ Kb, __bf16* __restrict__ Vt) {
  extern __shared__ __bf16 lds[];
  int t = threadIdx.x, wid = t >> 6, l = t & 63;
  int lr = l & 15, lg = l >> 4;
  int wm16 = (wid >> 2) * 16, wn64 = (wid & 3) * 64;
  int bid = blockIdx.x;
  int xcd = bid & 7, idx = bid >> 3;            // 96 blocks per XCD
  int res = idx & 31, grp = idx >> 5;           // grp 0..2
  int row0 = (xcd * 4 + (res >> 3)) * 256;      // same for idx, idx+32, idx+64
  int col0 = (grp * 8 + (res & 7)) * 256;       // 24 cols covered
  v4f acc[8][4];
  gemm256q_core(A, Bm, row0, col0, lds, acc, wm16, wn64, lr, lg);

  if (col0 >= 4096) {
    // ---- V blocks ----
    int h0 = (col0 & 2047) >> 7;
    int bb = row0 >> 11;
    int t0 = row0 & 2047;
    int d_r = t >> 1, half = t & 1;
    int hh = h0 + (d_r >> 7), dd = d_r & 127;
#pragma unroll
    for (int mm = 0; mm < 8; ++mm) {
      __syncthreads();   // first: all waves past vmcnt(0); later: prev reads done
#pragma unroll
      for (int n = 0; n < 4; ++n) {
        int d_loc = wn64 + n * 16 + lr;
        float bv = bias[col0 + d_loc];
        v4bf pv = {(__bf16)(acc[mm][n][0] + bv), (__bf16)(acc[mm][n][1] + bv),
                   (__bf16)(acc[mm][n][2] + bv), (__bf16)(acc[mm][n][3] + bv)};
        *(v4bf*)&lds[d_loc * 40 + wm16 + lg * 4] = pv;
      }
      __syncthreads();
      size_t vbase = ((size_t)((bb * NHEAD + hh) * DHEAD + dd)) * T_SEQ
                   + t0 + mm * 32 + half * 16;
      v8bf x0 = *(const v8bf*)&lds[d_r * 40 + half * 16];
      v8bf x1 = *(const v8bf*)&lds[d_r * 40 + half * 16 + 8];
      *(v8bf*)&Vt[vbase] = x0;
      *(v8bf*)&Vt[vbase + 8] = x1;
    }
    return;
  }

  // ---- Q/K blocks: fused bias + RoPE (table), lane-per-column-pair ----
  __syncthreads();   // ALL waves past vmcnt(0): stale tail glds landed in lds
#pragma unroll
  for (int n = 0; n < 4; ++n) {
    int c_loc = wn64 + n * 16 + lr;
    float bv = bias[col0 + c_loc];
#pragma unroll
    for (int mm = 0; mm < 8; ++mm) {
#pragma unroll
      for (int rr = 0; rr < 4; ++rr) {
        int r_loc = wm16 + mm * 32 + lg * 4 + rr;
        *(__bf16*)((char*)lds + r_loc * 512 + ((2 * c_loc) ^ ((r_loc & 31) << 4)))
            = (__bf16)(acc[mm][n][rr] + bv);
      }
    }
  }
  __syncthreads();
  {
    int tensor = col0 >> 11;                     // 0=Q, 1=K
    int h0 = (col0 & 2047) >> 7;
    int bb = row0 >> 11;
    int t0 = row0 & 2047;
    __bf16* QK = tensor ? Kb : Qb;
    int d = l;                                   // lane = output col pair (2d,2d+1)
    float sgn = (d < 32) ? -1.f : 1.f;           // cols<64: -cms ; cols>=64: +cms
    int mOff = 4 * d;                            // byte of x[2d] within head base
    int pOff = (d < 32) ? (8 * d) : (8 * d - 256);  // partner quad byte base
    int tOff = ((2 * d) & 63) * 8;               // table byte offset (j = c mod 64)
#pragma unroll 4
    for (int i = 0; i < 64; ++i) {
      int p = wid * 64 + i;                      // 0..511 (head-half, row)
      int u = p >> 8, r = p & 255;
      int tt = t0 + r;
      const char* lrow_ = (const char*)lds + r * 512;
      int swz = (r & 31) << 4;
      int cb = u * 256;
      v2bf xm = *(const v2bf*)(lrow_ + ((cb + mOff) ^ swz));   // x[2d], x[2d+1]
      v4bf xp = *(const v4bf*)(lrow_ + ((cb + pOff) ^ swz));   // partner quad
      float4 tv = *(const float4*)((const char*)(rt + (size_t)tt * 64) + tOff);
      float p1 = (d < 32) ? (float)xp[1] : (float)xp[0];       // x[2c1+1] | x[2c1-128]
      float p2 = (d < 32) ? (float)xp[3] : (float)xp[2];
      float o1 = (float)xm[0] * tv.x + sgn * p1 * tv.y;
      float o2 = (float)xm[1] * tv.z + sgn * p2 * tv.w;
      v2bf ov = {(__bf16)o1, (__bf16)o2};
      __bf16* dst = QK + ((size_t)(bb * NHEAD + h0 + u) * T_SEQ + tt) * DHEAD;
      *(v2bf*)(dst + 2 * d) = ov;
    }
  }
}

// GEMM2: out = Y * w_proj^T + b_proj, fp32 row-major epilogue; XCD-chunked map.
__global__ __launch_bounds__(512, 2) void gemm_out8(
    const __bf16* __restrict__ A, const __bf16* __restrict__ Bm,
    const float* __restrict__ bias, float* __restrict__ C) {
  extern __shared__ __bf16 lds[];
  int t = threadIdx.x, wid = t >> 6, l = t & 63;
  int lr = l & 15, lg = l >> 4;
  int wm16 = (wid >> 2) * 16, wn64 = (wid & 3) * 64;
  int bid = blockIdx.x;
  int xcd = bid & 7, idx = bid >> 3;            // 32 blocks per XCD
  int row0 = (xcd * 4 + idx / 8) * 256;
  int col0 = (idx % 8) * 256;
  v4f acc[8][4];
  gemm256_core(A, Bm, row0, col0, lds, acc, wm16, wn64, lr, lg);
#pragma unroll
  for (int n = 0; n < 4; ++n) {
    int col = col0 + wn64 + n * 16 + lr;
    float bv = bias[col];
#pragma unroll
    for (int mm = 0; mm < 8; ++mm) {
#pragma unroll
      for (int rr = 0; rr < 4; ++rr) {
        int mg = row0 + wm16 + mm * 32 + lg * 4 + rr;
        C[(size_t)mg * CDIM + col] = acc[mm][n][rr] + bv;
      }
    }
  }
}

// ---------------- flash attention v6 -----------------------------------------
// 512 thr = 8 waves, 256 q-rows/block; complementary CU pairing (r8);
// T14 reg-prefetch (r9); T5 setprio (r13); shrunk plds + rcp epilogue (r15).
__global__ __launch_bounds__(512, 2) void attn_fwd(
    const __bf16* __restrict__ Qb, const __bf16* __restrict__ Kb,
    const __bf16* __restrict__ Vt, __bf16* __restrict__ Y) {
  __shared__ __bf16 lK[64 * 128];       // 16 KB, [kv][d] swizzled
  __shared__ __bf16 lV[128 * 64];       // 16 KB, [d][kv] swizzled
  __shared__ __bf16 plds[8][16][72];    // 18 KB, per-wave P scratch
  int t = threadIdx.x, w = t >> 6, l = t & 63;
  int lr = l & 15, lg = l >> 4;
  int id = blockIdx.x;                        // 0..511
  int xcd = id & 7, s = id >> 3;
  int bh = xcd * 8 + (s & 7);
  int g = s >> 3;
  int k = (g < 4) ? (7 - g) : (g - 4);
  int qb = k * 256;
  int b = bh >> 4, h = bh & 15;
  int q0 = qb + w * 32;
  const __bf16* Qh = Qb + (size_t)bh * T_SEQ * DHEAD;
  const __bf16* Kh = Kb + (size_t)bh * T_SEQ * DHEAD;
  const __bf16* Vh = Vt + (size_t)bh * DHEAD * T_SEQ;

  v8bf qf[2][4];
#pragma unroll
  for (int j = 0; j < 2; ++j)
#pragma unroll
    for (int c = 0; c < 4; ++c)
      qf[j][c] = *(const v8bf*)&Qh[(size_t)(q0 + j * 16 + lr) * DHEAD + c * 32 + lg * 8];

  v4f o[2][8];
#pragma unroll
  for (int j = 0; j < 2; ++j)
#pragma unroll
    for (int c = 0; c < 8; ++c) o[j][c] = (v4f){0.f, 0.f, 0.f, 0.f};
  float mrow[2] = {-1e30f, -1e30f}, lrow[2] = {0.f, 0.f};
  const float SCALE2 = 0.12751743f;   // (1/sqrt(128)) * log2(e)

  int kRow = t >> 4;                                       // 0..31
  int kSrc = (((t & 15) * 16) ^ ((kRow & 7) << 4)) >> 1;
  int vRow = t >> 3;                                       // 0..63
  int vSrc = (((t & 7) * 16) ^ ((vRow & 7) << 4)) >> 1;
  __bf16* lKd0 = lK + w * 512 + l * 8;
  __bf16* lKd1 = lK + 4096 + w * 512 + l * 8;
  __bf16* lVd0 = lV + w * 512 + l * 8;
  __bf16* lVd1 = lV + 4096 + w * 512 + l * 8;

  // prologue: tile 0 -> regs
  v8bf kr0 = *(const v8bf*)&Kh[(size_t)(kRow) * DHEAD + kSrc];
  v8bf kr1 = *(const v8bf*)&Kh[(size_t)(32 + kRow) * DHEAD + kSrc];
  v8bf vr0 = *(const v8bf*)&Vh[(size_t)(vRow) * T_SEQ + vSrc];
  v8bf vr1 = *(const v8bf*)&Vh[(size_t)(64 + vRow) * T_SEQ + vSrc];

  int kvEnd = qb + 192;
  for (int kv0 = 0; kv0 <= kvEnd; kv0 += 64) {
    __syncthreads();                       // prior tile fully consumed
    *(v8bf*)lKd0 = kr0; *(v8bf*)lKd1 = kr1;
    *(v8bf*)lVd0 = vr0; *(v8bf*)lVd1 = vr1;
    __syncthreads();                       // tile visible
    if (kv0 + 64 <= kvEnd) {               // prefetch next tile (wave-uniform)
      kr0 = *(const v8bf*)&Kh[(size_t)(kv0 + 64 + kRow) * DHEAD + kSrc];
      kr1 = *(const v8bf*)&Kh[(size_t)(kv0 + 96 + kRow) * DHEAD + kSrc];
      vr0 = *(const v8bf*)&Vh[(size_t)(vRow) * T_SEQ + kv0 + 64 + vSrc];
      vr1 = *(const v8bf*)&Vh[(size_t)(64 + vRow) * T_SEQ + kv0 + 64 + vSrc];
    }

    if (kv0 <= q0 + 31) {
      // ---- QK^T (swapped): S[64 kv][32 q] ----
      v4f s2[2][4];
#pragma unroll
      for (int j = 0; j < 2; ++j)
#pragma unroll
        for (int f = 0; f < 4; ++f) s2[j][f] = (v4f){0.f, 0.f, 0.f, 0.f};
      __builtin_amdgcn_s_setprio(1);
#pragma unroll
      for (int f = 0; f < 4; ++f) {
        int row = f * 16 + lr;
        int sw = (row & 7) << 4;
#pragma unroll
        for (int c = 0; c < 4; ++c) {
          v8bf kf = *(const v8bf*)((const char*)lK + row * 256 + ((c * 64 + lg * 16) ^ sw));
          s2[0][f] = MFMA16(kf, qf[0][c], s2[0][f]);
          s2[1][f] = MFMA16(kf, qf[1][c], s2[1][f]);
        }
      }
      __builtin_amdgcn_s_setprio(0);

      v8bf pa[2][2];
#pragma unroll
      for (int j = 0; j < 2; ++j) {
        int qg = q0 + j * 16 + lr;
        bool needMask = (kv0 + 63 > q0 + j * 16);
        float p[16];
        float mt = -1e30f;
#pragma unroll
        for (int f = 0; f < 4; ++f)
#pragma unroll
          for (int r = 0; r < 4; ++r) {
            float v = s2[j][f][r] * SCALE2;
            if (needMask && (kv0 + f * 16 + lg * 4 + r > qg)) v = -1e30f;
            p[f * 4 + r] = v;
            mt = fmaxf(mt, v);
          }
        mt = fmaxf(mt, __shfl_xor(mt, 16));
        mt = fmaxf(mt, __shfl_xor(mt, 32));
        if (!__all(mt <= mrow[j] + 8.0f)) {      // rescale (rare after warmup)
          float mnew = fmaxf(mrow[j], mt);
          float corr = exp2f(mrow[j] - mnew);
          mrow[j] = mnew;
          lrow[j] *= corr;
          float cf[4];
#pragma unroll
          for (int r = 0; r < 4; ++r) cf[r] = __shfl(corr, lg * 4 + r);
#pragma unroll
          for (int c = 0; c < 8; ++c)
#pragma unroll
            for (int r = 0; r < 4; ++r) o[j][c][r] *= cf[r];
        }
        float psum = 0.f;
#pragma unroll
        for (int r = 0; r < 16; ++r) { p[r] = exp2f(p[r] - mrow[j]); psum += p[r]; }
        psum += __shfl_xor(psum, 16);
        psum += __shfl_xor(psum, 32);
        lrow[j] += psum;
#pragma unroll
        for (int f = 0; f < 4; ++f) {
          v4bf pv = {(__bf16)p[f * 4], (__bf16)p[f * 4 + 1],
                     (__bf16)p[f * 4 + 2], (__bf16)p[f * 4 + 3]};
          *(v4bf*)&plds[w][lr][f * 16 + lg * 4] = pv;
        }
        asm volatile("s_waitcnt lgkmcnt(0)" ::: "memory");
        pa[j][0] = *(const v8bf*)&plds[w][lr][lg * 8];
        pa[j][1] = *(const v8bf*)&plds[w][lr][32 + lg * 8];
      }

      // ---- PV ----
      __builtin_amdgcn_s_setprio(1);
#pragma unroll
      for (int c = 0; c < 8; ++c) {
        int row = c * 16 + lr;
        int sw = (row & 7) << 4;
        v8bf vf0 = *(const v8bf*)((const char*)lV + row * 128 + ((lg * 16) ^ sw));
        v8bf vf1 = *(const v8bf*)((const char*)lV + row * 128 + ((64 + lg * 16) ^ sw));
        o[0][c] = MFMA16(pa[0][0], vf0, o[0][c]);
        o[0][c] = MFMA16(pa[0][1], vf1, o[0][c]);
        o[1][c] = MFMA16(pa[1][0], vf0, o[1][c]);
        o[1][c] = MFMA16(pa[1][1], vf1, o[1][c]);
      }
      __builtin_amdgcn_s_setprio(0);
    }
  }

  size_t ybase = ((size_t)b * T_SEQ) * CDIM + (size_t)h * DHEAD;
#pragma unroll
  for (int j = 0; j < 2; ++j) {
    float rf[4];
#pragma unroll
    for (int r = 0; r < 4; ++r)
      rf[r] = __builtin_amdgcn_rcpf(__shfl(lrow[j], lg * 4 + r));
#pragma unroll
    for (int c = 0; c < 8; ++c) {
#pragma unroll
      for (int r = 0; r < 4; ++r) {
        int qq = q0 + j * 16 + lg * 4 + r;
        Y[ybase + (size_t)qq * CDIM + c * 16 + lr] = (__bf16)(o[j][c][r] * rf[r]);
      }
    }
  }
}

// ---------------- launch -----------------------------------------------------
extern "C" void kernel_launch(void* const* d_in, const int* in_sizes, int n_in,
                              void* d_out, int out_size, void* d_ws, size_t ws_size,
                              hipStream_t stream) {
  const float* x      = (const float*)d_in[0];
  const float* w_attn = (const float*)d_in[1];
  const float* b_attn = (const float*)d_in[2];
  const float* w_proj = (const float*)d_in[3];
  const float* b_proj = (const float*)d_in[4];
  float* out = (float*)d_out;

  char* ws = (char*)d_ws;
  __bf16* xbf  = (__bf16*)(ws);                 // 33,554,432 B; reused as Y
  __bf16* wabf = (__bf16*)(ws + 33554432);      // 25,165,824 B
  __bf16* wpbf = (__bf16*)(ws + 58720256);      //  8,388,608 B
  __bf16* Qb   = (__bf16*)(ws + 67108864);      // 33,554,432 B (BH,T,D)
  __bf16* Kb   = (__bf16*)(ws + 100663296);     // 33,554,432 B (BH,T,D)
  __bf16* Vt   = (__bf16*)(ws + 134217728);     // 33,554,432 B (BH,D,T)
  float2* rtab = (float2*)(ws + 167772160);     //  1,048,576 B rope table
  __bf16* Y    = xbf;

  (void)hipFuncSetAttribute((const void*)gemm_qkv8,
                            hipFuncAttributeMaxDynamicSharedMemorySize, 131072);
  (void)hipFuncSetAttribute((const void*)gemm_out8,
                            hipFuncAttributeMaxDynamicSharedMemorySize, 131072);

  cvt_all<<<2048, 256, 0, stream>>>(x, w_attn, w_proj, xbf, wabf, wpbf, rtab);

  gemm_qkv8<<<768, 512, 131072, stream>>>(xbf, wabf, b_attn, rtab, Qb, Kb, Vt);

  attn_fwd<<<512, 512, 0, stream>>>(Qb, Kb, Vt, Y);

  gemm_out8<<<256, 512, 131072, stream>>>(Y, wpbf, b_proj, out);
}

// Round 17
// 420.974 us; speedup vs baseline: 1.0720x; 1.0720x over previous
//
#include <hip/hip_runtime.h>

// Problem constants: B=4, T=2048, C=2048, H=16, D=128
#define T_SEQ 2048
#define DHEAD 128
#define NHEAD 16
#define CDIM  2048
#define BATCH 4

typedef __bf16 v8bf __attribute__((ext_vector_type(8)));
typedef __bf16 v4bf __attribute__((ext_vector_type(4)));
typedef __bf16 v2bf __attribute__((ext_vector_type(2)));
typedef float  v4f  __attribute__((ext_vector_type(4)));

#define MFMA16(a,b,c) __builtin_amdgcn_mfma_f32_16x16x32_bf16(a,b,c,0,0,0)
#define GLDS16(g,l) __builtin_amdgcn_global_load_lds( \
    (__attribute__((address_space(1))) void*)(g), \
    (__attribute__((address_space(3))) void*)(l), 16, 0, 0)

// ------- fused f32 -> bf16 convert (x, w_attn, w_proj) + RoPE table ---------
__global__ __launch_bounds__(256) void cvt_all(const float* __restrict__ x,
                                               const float* __restrict__ wa,
                                               const float* __restrict__ wp,
                                               __bf16* __restrict__ xo,
                                               __bf16* __restrict__ wao,
                                               __bf16* __restrict__ wpo,
                                               float2* __restrict__ rt) {
  int i = blockIdx.x * 256 + threadIdx.x;
  int stride = gridDim.x * 256;
  for (int j = i; j < 8519680; j += stride) {   // 8388608 float4s + 131072 tab
    if (j < 8388608) {
      const float* src; __bf16* dst; int off;
      if (j < 4194304)      { src = x;  dst = xo;  off = j; }
      else if (j < 7340032) { src = wa; dst = wao; off = j - 4194304; }
      else                  { src = wp; dst = wpo; off = j - 7340032; }
      float4 v = *(const float4*)(src + (size_t)off * 4);
      v4bf o = {(__bf16)v.x, (__bf16)v.y, (__bf16)v.z, (__bf16)v.w};
      *(v4bf*)(dst + (size_t)off * 4) = o;
    } else {
      int e = j - 8388608;                     // 0..131071
      int tt = e >> 6, jj = e & 63;
      float invf = exp2f((float)jj * (-13.287712379549449f / 64.f));
      float ang = (float)tt * invf;
      float c = cosf(ang), s = sinf(ang);
      rt[e] = make_float2(c + s, c - s);
    }
  }
}

// =============== 256x256 8-phase GEMM core (m201 template, plain HIP) =======
#define LGKM0() { asm volatile("s_waitcnt lgkmcnt(0)" ::: "memory"); \
                  __builtin_amdgcn_sched_barrier(0); }
#define BARR()  { __builtin_amdgcn_s_barrier(); __builtin_amdgcn_sched_barrier(0); }

#define RDA(mm, kk) (*(const v8bf*)(bA + (wm16 + (mm)*32 + lr) * 128 + ((((kk)*64) + lgc) ^ swl)))
#define RDB(n, kk)  (*(const v8bf*)(bB + (wn64 + (n)*16 + lr) * 128 + ((((kk)*64) + lgc) ^ swl)))
#define MF(mm,n,kk) acc[mm][n] = MFMA16(af[(mm)&1][kk], bfr[n][kk], acc[mm][n]);

#define PH_MFMA(MM0, MM1) \
  BARR(); LGKM0(); \
  __builtin_amdgcn_s_setprio(1); \
  MF(MM0,0,0) MF(MM0,1,0) MF(MM0,2,0) MF(MM0,3,0) \
  MF(MM1,0,0) MF(MM1,1,0) MF(MM1,2,0) MF(MM1,3,0) \
  MF(MM0,0,1) MF(MM0,1,1) MF(MM0,2,1) MF(MM0,3,1) \
  MF(MM1,0,1) MF(MM1,1,1) MF(MM1,2,1) MF(MM1,3,1) \
  __builtin_amdgcn_s_setprio(0); \
  BARR();

#define STAGE_H(SRC, ks, hh, LBASE) { \
  GLDS16((SRC) + (size_t)((hh)*128)      * 2048 + (size_t)(ks)*64, lds + (LBASE) + dst0); \
  GLDS16((SRC) + (size_t)((hh)*128 + 64) * 2048 + (size_t)(ks)*64, lds + (LBASE) + 4096 + dst0); }

#define TILE(CB, ks1, ks2) { \
  const char* bA = (const char*)(lds + (CB)*32768); \
  const char* bB = bA + 32768; \
  v8bf bfr[4][2], af[2][2]; \
  af[0][0]=RDA(0,0); af[0][1]=RDA(0,1); af[1][0]=RDA(1,0); af[1][1]=RDA(1,1); \
  bfr[0][0]=RDB(0,0); bfr[0][1]=RDB(0,1); bfr[1][0]=RDB(1,0); bfr[1][1]=RDB(1,1); \
  bfr[2][0]=RDB(2,0); bfr[2][1]=RDB(2,1); bfr[3][0]=RDB(3,0); bfr[3][1]=RDB(3,1); \
  STAGE_H(Asrc, ks1, 1, ((CB)^1)*32768 + 8192); \
  PH_MFMA(0, 1) \
  af[0][0]=RDA(2,0); af[0][1]=RDA(2,1); af[1][0]=RDA(3,0); af[1][1]=RDA(3,1); \
  STAGE_H(Bsrc, ks2, 0, (CB)*32768 + 16384); \
  PH_MFMA(2, 3) \
  af[0][0]=RDA(4,0); af[0][1]=RDA(4,1); af[1][0]=RDA(5,0); af[1][1]=RDA(5,1); \
  STAGE_H(Asrc, ks2, 0, (CB)*32768); \
  PH_MFMA(4, 5) \
  af[0][0]=RDA(6,0); af[0][1]=RDA(6,1); af[1][0]=RDA(7,0); af[1][1]=RDA(7,1); \
  STAGE_H(Bsrc, ks2, 1, (CB)*32768 + 24576); \
  asm volatile("s_waitcnt vmcnt(6)" ::: "memory"); \
  PH_MFMA(6, 7) \
}

__device__ __forceinline__ void gemm256_core(
    const __bf16* __restrict__ A, const __bf16* __restrict__ Bm,
    int row0, int col0, __bf16* lds, v4f (&acc)[8][4],
    int wm16, int wn64, int lr, int lg) {
  int t = threadIdx.x;
  int wid = t >> 6;
  int lgc = lg * 16;
  int swl = (lr & 7) << 4;
#pragma unroll
  for (int mm = 0; mm < 8; ++mm)
#pragma unroll
    for (int n = 0; n < 4; ++n) acc[mm][n] = (v4f){0.f, 0.f, 0.f, 0.f};

  int srow = t >> 3;
  int scol = (((t & 7) ^ ((t >> 3) & 7)) << 3);
  const __bf16* Asrc = A  + (size_t)(row0 + srow) * 2048 + scol;
  const __bf16* Bsrc = Bm + (size_t)(col0 + srow) * 2048 + scol;
  int dst0 = wid << 9;

  STAGE_H(Asrc, 0, 0, 0);
  STAGE_H(Asrc, 0, 1, 8192);
  STAGE_H(Bsrc, 0, 0, 16384);
  STAGE_H(Bsrc, 0, 1, 24576);
  STAGE_H(Bsrc, 1, 0, 32768 + 16384);
  STAGE_H(Asrc, 1, 0, 32768);
  STAGE_H(Bsrc, 1, 1, 32768 + 24576);
  asm volatile("s_waitcnt vmcnt(6)" ::: "memory");
  BARR();

  for (int m = 0; m < 32; m += 2) {
    TILE(0, m + 1, (m + 2) & 31)
    TILE(1, (m + 2) & 31, (m + 3) & 31)
  }
  asm volatile("s_waitcnt vmcnt(0)" ::: "memory");
}

// GEMM1: qkv = x * w_attn^T + b_attn.
// r15 grid map: CU's 3 sequential blocks share one A-panel (L2-resident).
// Q/K: fused bias+RoPE epilogue, lane = column-pair (r12).
// V: LDS-transposed coalesced store to Vt (BH,D,T).
// (r16's reg-staged B experiment regressed 197->238 us; reverted to r15.)
__global__ __launch_bounds__(512, 2) void gemm_qkv8(
    const __bf16* __restrict__ A, const __bf16* __restrict__ Bm,
    const float* __restrict__ bias, const float2* __restrict__ rt,
    __bf16* __restrict__ Qb, __bf16* __restrict__ Kb, __bf16* __restrict__ Vt) {
  extern __shared__ __bf16 lds[];
  int t = threadIdx.x, wid = t >> 6, l = t & 63;
  int lr = l & 15, lg = l >> 4;
  int wm16 = (wid >> 2) * 16, wn64 = (wid & 3) * 64;
  int bid = blockIdx.x;
  int xcd = bid & 7, idx = bid >> 3;            // 96 blocks per XCD
  int res = idx & 31, grp = idx >> 5;           // grp 0..2
  int row0 = (xcd * 4 + (res >> 3)) * 256;      // same for idx, idx+32, idx+64
  int col0 = (grp * 8 + (res & 7)) * 256;       // 24 cols covered
  v4f acc[8][4];
  gemm256_core(A, Bm, row0, col0, lds, acc, wm16, wn64, lr, lg);

  if (col0 >= 4096) {
    // ---- V blocks ----
    int h0 = (col0 & 2047) >> 7;
    int bb = row0 >> 11;
    int t0 = row0 & 2047;
    int d_r = t >> 1, half = t & 1;
    int hh = h0 + (d_r >> 7), dd = d_r & 127;
#pragma unroll
    for (int mm = 0; mm < 8; ++mm) {
      __syncthreads();   // first: all waves past vmcnt(0); later: prev reads done
#pragma unroll
      for (int n = 0; n < 4; ++n) {
        int d_loc = wn64 + n * 16 + lr;
        float bv = bias[col0 + d_loc];
        v4bf pv = {(__bf16)(acc[mm][n][0] + bv), (__bf16)(acc[mm][n][1] + bv),
                   (__bf16)(acc[mm][n][2] + bv), (__bf16)(acc[mm][n][3] + bv)};
        *(v4bf*)&lds[d_loc * 40 + wm16 + lg * 4] = pv;
      }
      __syncthreads();
      size_t vbase = ((size_t)((bb * NHEAD + hh) * DHEAD + dd)) * T_SEQ
                   + t0 + mm * 32 + half * 16;
      v8bf x0 = *(const v8bf*)&lds[d_r * 40 + half * 16];
      v8bf x1 = *(const v8bf*)&lds[d_r * 40 + half * 16 + 8];
      *(v8bf*)&Vt[vbase] = x0;
      *(v8bf*)&Vt[vbase + 8] = x1;
    }
    return;
  }

  // ---- Q/K blocks: fused bias + RoPE (table), lane-per-column-pair ----
  __syncthreads();   // ALL waves past vmcnt(0): stale tail glds landed in lds
#pragma unroll
  for (int n = 0; n < 4; ++n) {
    int c_loc = wn64 + n * 16 + lr;
    float bv = bias[col0 + c_loc];
#pragma unroll
    for (int mm = 0; mm < 8; ++mm) {
#pragma unroll
      for (int rr = 0; rr < 4; ++rr) {
        int r_loc = wm16 + mm * 32 + lg * 4 + rr;
        *(__bf16*)((char*)lds + r_loc * 512 + ((2 * c_loc) ^ ((r_loc & 31) << 4)))
            = (__bf16)(acc[mm][n][rr] + bv);
      }
    }
  }
  __syncthreads();
  {
    int tensor = col0 >> 11;                     // 0=Q, 1=K
    int h0 = (col0 & 2047) >> 7;
    int bb = row0 >> 11;
    int t0 = row0 & 2047;
    __bf16* QK = tensor ? Kb : Qb;
    int d = l;                                   // lane = output col pair (2d,2d+1)
    float sgn = (d < 32) ? -1.f : 1.f;           // cols<64: -cms ; cols>=64: +cms
    int mOff = 4 * d;                            // byte of x[2d] within head base
    int pOff = (d < 32) ? (8 * d) : (8 * d - 256);  // partner quad byte base
    int tOff = ((2 * d) & 63) * 8;               // table byte offset (j = c mod 64)
#pragma unroll 4
    for (int i = 0; i < 64; ++i) {
      int p = wid * 64 + i;                      // 0..511 (head-half, row)
      int u = p >> 8, r = p & 255;
      int tt = t0 + r;
      const char* lrow_ = (const char*)lds + r * 512;
      int swz = (r & 31) << 4;
      int cb = u * 256;
      v2bf xm = *(const v2bf*)(lrow_ + ((cb + mOff) ^ swz));   // x[2d], x[2d+1]
      v4bf xp = *(const v4bf*)(lrow_ + ((cb + pOff) ^ swz));   // partner quad
      float4 tv = *(const float4*)((const char*)(rt + (size_t)tt * 64) + tOff);
      float p1 = (d < 32) ? (float)xp[1] : (float)xp[0];       // x[2c1+1] | x[2c1-128]
      float p2 = (d < 32) ? (float)xp[3] : (float)xp[2];
      float o1 = (float)xm[0] * tv.x + sgn * p1 * tv.y;
      float o2 = (float)xm[1] * tv.z + sgn * p2 * tv.w;
      v2bf ov = {(__bf16)o1, (__bf16)o2};
      __bf16* dst = QK + ((size_t)(bb * NHEAD + h0 + u) * T_SEQ + tt) * DHEAD;
      *(v2bf*)(dst + 2 * d) = ov;
    }
  }
}

// GEMM2: out = Y * w_proj^T + b_proj, fp32 row-major epilogue; XCD-chunked map.
__global__ __launch_bounds__(512, 2) void gemm_out8(
    const __bf16* __restrict__ A, const __bf16* __restrict__ Bm,
    const float* __restrict__ bias, float* __restrict__ C) {
  extern __shared__ __bf16 lds[];
  int t = threadIdx.x, wid = t >> 6, l = t & 63;
  int lr = l & 15, lg = l >> 4;
  int wm16 = (wid >> 2) * 16, wn64 = (wid & 3) * 64;
  int bid = blockIdx.x;
  int xcd = bid & 7, idx = bid >> 3;            // 32 blocks per XCD
  int row0 = (xcd * 4 + idx / 8) * 256;
  int col0 = (idx % 8) * 256;
  v4f acc[8][4];
  gemm256_core(A, Bm, row0, col0, lds, acc, wm16, wn64, lr, lg);
#pragma unroll
  for (int n = 0; n < 4; ++n) {
    int col = col0 + wn64 + n * 16 + lr;
    float bv = bias[col];
#pragma unroll
    for (int mm = 0; mm < 8; ++mm) {
#pragma unroll
      for (int rr = 0; rr < 4; ++rr) {
        int mg = row0 + wm16 + mm * 32 + lg * 4 + rr;
        C[(size_t)mg * CDIM + col] = acc[mm][n][rr] + bv;
      }
    }
  }
}

// ---------------- flash attention v6 -----------------------------------------
// 512 thr = 8 waves, 256 q-rows/block; complementary CU pairing (r8);
// T14 reg-prefetch (r9); T5 setprio (r13); shrunk plds + rcp epilogue (r15).
__global__ __launch_bounds__(512, 2) void attn_fwd(
    const __bf16* __restrict__ Qb, const __bf16* __restrict__ Kb,
    const __bf16* __restrict__ Vt, __bf16* __restrict__ Y) {
  __shared__ __bf16 lK[64 * 128];       // 16 KB, [kv][d] swizzled
  __shared__ __bf16 lV[128 * 64];       // 16 KB, [d][kv] swizzled
  __shared__ __bf16 plds[8][16][72];    // 18 KB, per-wave P scratch
  int t = threadIdx.x, w = t >> 6, l = t & 63;
  int lr = l & 15, lg = l >> 4;
  int id = blockIdx.x;                        // 0..511
  int xcd = id & 7, s = id >> 3;
  int bh = xcd * 8 + (s & 7);
  int g = s >> 3;
  int k = (g < 4) ? (7 - g) : (g - 4);
  int qb = k * 256;
  int b = bh >> 4, h = bh & 15;
  int q0 = qb + w * 32;
  const __bf16* Qh = Qb + (size_t)bh * T_SEQ * DHEAD;
  const __bf16* Kh = Kb + (size_t)bh * T_SEQ * DHEAD;
  const __bf16* Vh = Vt + (size_t)bh * DHEAD * T_SEQ;

  v8bf qf[2][4];
#pragma unroll
  for (int j = 0; j < 2; ++j)
#pragma unroll
    for (int c = 0; c < 4; ++c)
      qf[j][c] = *(const v8bf*)&Qh[(size_t)(q0 + j * 16 + lr) * DHEAD + c * 32 + lg * 8];

  v4f o[2][8];
#pragma unroll
  for (int j = 0; j < 2; ++j)
#pragma unroll
    for (int c = 0; c < 8; ++c) o[j][c] = (v4f){0.f, 0.f, 0.f, 0.f};
  float mrow[2] = {-1e30f, -1e30f}, lrow[2] = {0.f, 0.f};
  const float SCALE2 = 0.12751743f;   // (1/sqrt(128)) * log2(e)

  int kRow = t >> 4;                                       // 0..31
  int kSrc = (((t & 15) * 16) ^ ((kRow & 7) << 4)) >> 1;
  int vRow = t >> 3;                                       // 0..63
  int vSrc = (((t & 7) * 16) ^ ((vRow & 7) << 4)) >> 1;
  __bf16* lKd0 = lK + w * 512 + l * 8;
  __bf16* lKd1 = lK + 4096 + w * 512 + l * 8;
  __bf16* lVd0 = lV + w * 512 + l * 8;
  __bf16* lVd1 = lV + 4096 + w * 512 + l * 8;

  // prologue: tile 0 -> regs
  v8bf kr0 = *(const v8bf*)&Kh[(size_t)(kRow) * DHEAD + kSrc];
  v8bf kr1 = *(const v8bf*)&Kh[(size_t)(32 + kRow) * DHEAD + kSrc];
  v8bf vr0 = *(const v8bf*)&Vh[(size_t)(vRow) * T_SEQ + vSrc];
  v8bf vr1 = *(const v8bf*)&Vh[(size_t)(64 + vRow) * T_SEQ + vSrc];

  int kvEnd = qb + 192;
  for (int kv0 = 0; kv0 <= kvEnd; kv0 += 64) {
    __syncthreads();                       // prior tile fully consumed
    *(v8bf*)lKd0 = kr0; *(v8bf*)lKd1 = kr1;
    *(v8bf*)lVd0 = vr0; *(v8bf*)lVd1 = vr1;
    __syncthreads();                       // tile visible
    if (kv0 + 64 <= kvEnd) {               // prefetch next tile (wave-uniform)
      kr0 = *(const v8bf*)&Kh[(size_t)(kv0 + 64 + kRow) * DHEAD + kSrc];
      kr1 = *(const v8bf*)&Kh[(size_t)(kv0 + 96 + kRow) * DHEAD + kSrc];
      vr0 = *(const v8bf*)&Vh[(size_t)(vRow) * T_SEQ + kv0 + 64 + vSrc];
      vr1 = *(const v8bf*)&Vh[(size_t)(64 + vRow) * T_SEQ + kv0 + 64 + vSrc];
    }

    if (kv0 <= q0 + 31) {
      // ---- QK^T (swapped): S[64 kv][32 q] ----
      v4f s2[2][4];
#pragma unroll
      for (int j = 0; j < 2; ++j)
#pragma unroll
        for (int f = 0; f < 4; ++f) s2[j][f] = (v4f){0.f, 0.f, 0.f, 0.f};
      __builtin_amdgcn_s_setprio(1);
#pragma unroll
      for (int f = 0; f < 4; ++f) {
        int row = f * 16 + lr;
        int sw = (row & 7) << 4;
#pragma unroll
        for (int c = 0; c < 4; ++c) {
          v8bf kf = *(const v8bf*)((const char*)lK + row * 256 + ((c * 64 + lg * 16) ^ sw));
          s2[0][f] = MFMA16(kf, qf[0][c], s2[0][f]);
          s2[1][f] = MFMA16(kf, qf[1][c], s2[1][f]);
        }
      }
      __builtin_amdgcn_s_setprio(0);

      v8bf pa[2][2];
#pragma unroll
      for (int j = 0; j < 2; ++j) {
        int qg = q0 + j * 16 + lr;
        bool needMask = (kv0 + 63 > q0 + j * 16);
        float p[16];
        float mt = -1e30f;
#pragma unroll
        for (int f = 0; f < 4; ++f)
#pragma unroll
          for (int r = 0; r < 4; ++r) {
            float v = s2[j][f][r] * SCALE2;
            if (needMask && (kv0 + f * 16 + lg * 4 + r > qg)) v = -1e30f;
            p[f * 4 + r] = v;
            mt = fmaxf(mt, v);
          }
        mt = fmaxf(mt, __shfl_xor(mt, 16));
        mt = fmaxf(mt, __shfl_xor(mt, 32));
        if (!__all(mt <= mrow[j] + 8.0f)) {      // rescale (rare after warmup)
          float mnew = fmaxf(mrow[j], mt);
          float corr = exp2f(mrow[j] - mnew);
          mrow[j] = mnew;
          lrow[j] *= corr;
          float cf[4];
#pragma unroll
          for (int r = 0; r < 4; ++r) cf[r] = __shfl(corr, lg * 4 + r);
#pragma unroll
          for (int c = 0; c < 8; ++c)
#pragma unroll
            for (int r = 0; r < 4; ++r) o[j][c][r] *= cf[r];
        }
        float psum = 0.f;
#pragma unroll
        for (int r = 0; r < 16; ++r) { p[r] = exp2f(p[r] - mrow[j]); psum += p[r]; }
        psum += __shfl_xor(psum, 16);
        psum += __shfl_xor(psum, 32);
        lrow[j] += psum;
#pragma unroll
        for (int f = 0; f < 4; ++f) {
          v4bf pv = {(__bf16)p[f * 4], (__bf16)p[f * 4 + 1],
                     (__bf16)p[f * 4 + 2], (__bf16)p[f * 4 + 3]};
          *(v4bf*)&plds[w][lr][f * 16 + lg * 4] = pv;
        }
        asm volatile("s_waitcnt lgkmcnt(0)" ::: "memory");
        pa[j][0] = *(const v8bf*)&plds[w][lr][lg * 8];
        pa[j][1] = *(const v8bf*)&plds[w][lr][32 + lg * 8];
      }

      // ---- PV ----
      __builtin_amdgcn_s_setprio(1);
#pragma unroll
      for (int c = 0; c < 8; ++c) {
        int row = c * 16 + lr;
        int sw = (row & 7) << 4;
        v8bf vf0 = *(const v8bf*)((const char*)lV + row * 128 + ((lg * 16) ^ sw));
        v8bf vf1 = *(const v8bf*)((const char*)lV + row * 128 + ((64 + lg * 16) ^ sw));
        o[0][c] = MFMA16(pa[0][0], vf0, o[0][c]);
        o[0][c] = MFMA16(pa[0][1], vf1, o[0][c]);
        o[1][c] = MFMA16(pa[1][0], vf0, o[1][c]);
        o[1][c] = MFMA16(pa[1][1], vf1, o[1][c]);
      }
      __builtin_amdgcn_s_setprio(0);
    }
  }

  size_t ybase = ((size_t)b * T_SEQ) * CDIM + (size_t)h * DHEAD;
#pragma unroll
  for (int j = 0; j < 2; ++j) {
    float rf[4];
#pragma unroll
    for (int r = 0; r < 4; ++r)
      rf[r] = __builtin_amdgcn_rcpf(__shfl(lrow[j], lg * 4 + r));
#pragma unroll
    for (int c = 0; c < 8; ++c) {
#pragma unroll
      for (int r = 0; r < 4; ++r) {
        int qq = q0 + j * 16 + lg * 4 + r;
        Y[ybase + (size_t)qq * CDIM + c * 16 + lr] = (__bf16)(o[j][c][r] * rf[r]);
      }
    }
  }
}

// ---------------- launch -----------------------------------------------------
extern "C" void kernel_launch(void* const* d_in, const int* in_sizes, int n_in,
                              void* d_out, int out_size, void* d_ws, size_t ws_size,
                              hipStream_t stream) {
  const float* x      = (const float*)d_in[0];
  const float* w_attn = (const float*)d_in[1];
  const float* b_attn = (const float*)d_in[2];
  const float* w_proj = (const float*)d_in[3];
  const float* b_proj = (const float*)d_in[4];
  float* out = (float*)d_out;

  char* ws = (char*)d_ws;
  __bf16* xbf  = (__bf16*)(ws);                 // 33,554,432 B; reused as Y
  __bf16* wabf = (__bf16*)(ws + 33554432);      // 25,165,824 B
  __bf16* wpbf = (__bf16*)(ws + 58720256);      //  8,388,608 B
  __bf16* Qb   = (__bf16*)(ws + 67108864);      // 33,554,432 B (BH,T,D)
  __bf16* Kb   = (__bf16*)(ws + 100663296);     // 33,554,432 B (BH,T,D)
  __bf16* Vt   = (__bf16*)(ws + 134217728);     // 33,554,432 B (BH,D,T)
  float2* rtab = (float2*)(ws + 167772160);     //  1,048,576 B rope table
  __bf16* Y    = xbf;

  (void)hipFuncSetAttribute((const void*)gemm_qkv8,
                            hipFuncAttributeMaxDynamicSharedMemorySize, 131072);
  (void)hipFuncSetAttribute((const void*)gemm_out8,
                            hipFuncAttributeMaxDynamicSharedMemorySize, 131072);

  cvt_all<<<2048, 256, 0, stream>>>(x, w_attn, w_proj, xbf, wabf, wpbf, rtab);

  gemm_qkv8<<<768, 512, 131072, stream>>>(xbf, wabf, b_attn, rtab, Qb, Kb, Vt);

  attn_fwd<<<512, 512, 0, stream>>>(Qb, Kb, Vt, Y);

  gemm_out8<<<256, 512, 131072, stream>>>(Y, wpbf, b_proj, out);
}